// Round 4
// baseline (255.011 us; speedup 1.0000x reference)
//
#include <hip/hip_runtime.h>
#include <hip/hip_bf16.h>
#include <float.h>

// Problem constants
constexpr int B  = 64;
constexpr int C  = 256;
constexpr int HW = 1024;   // 32*32
constexpr int K  = 1024;
constexpr float BETA = 0.25f;
constexpr float NTOT_INV = 1.0f / 16777216.0f;  // 1 / (64*256*32*32)

typedef __attribute__((ext_vector_type(8))) short bf16x8;
typedef __attribute__((ext_vector_type(4))) float floatx4;

union U16 { uint4 u; bf16x8 b; };

__device__ inline unsigned short f2bf(float x) {
    unsigned u = __float_as_uint(x);
    return (unsigned short)((u + 0x7FFFu + ((u >> 16) & 1u)) >> 16);  // RNE
}

// --- kernel 1: emb fp32 -> bf16 (row-major) + esq1[k] = 1 + ||e_k||^2 ---
// also zeroes loss accumulators + completion counter (block 0).
__global__ __launch_bounds__(256) void prep_kernel(const float* __restrict__ emb,
                                                   short* __restrict__ emb_bf,
                                                   float* __restrict__ esq1,
                                                   float* __restrict__ acc_loss) {
    if (blockIdx.x == 0 && threadIdx.x < 4) acc_loss[threadIdx.x] = 0.0f;
    const int wid  = threadIdx.x >> 6;
    const int lane = threadIdx.x & 63;
    const int k    = blockIdx.x * 4 + wid;
    const float4 v = *(const float4*)(emb + (size_t)k * C + lane * 4);
    ushort4 pk = { f2bf(v.x), f2bf(v.y), f2bf(v.z), f2bf(v.w) };
    *(ushort4*)(emb_bf + (size_t)k * C + lane * 4) = pk;
    float s = v.x * v.x + v.y * v.y + v.z * v.z + v.w * v.w;
#pragma unroll
    for (int off = 32; off > 0; off >>= 1) s += __shfl_down(s, off, 64);
    if (lane == 0) esq1[k] = 1.0f + s;
}

// --- kernel 2: 4-wave blocks; shared Z tile; K-split across waves ---
// grid: 1024 blocks x 256 thr. Block = 64 tokens; wave w scans codes [w*256, w*256+256).
__global__ __launch_bounds__(256, 2) void vq_main(const float* __restrict__ z,
                                                  const float* __restrict__ emb,
                                                  const short* __restrict__ emb_bf,
                                                  const float* __restrict__ esq1,
                                                  float* __restrict__ out,
                                                  float* __restrict__ acc_loss,
                                                  float* __restrict__ out_loss) {
    // transpose buffer: [32 ch-blocks][64 tok][8 ch] bf16 = 32 KB
    __shared__ short Zs[32 * 512];
    __shared__ unsigned int bestTok[64];
    __shared__ float wred[8];

    const int tid = threadIdx.x;
    const int w   = tid >> 6;      // wave 0..3
    const int L   = tid & 63;      // lane
    const int q   = L >> 4;        // quad
    const int l15 = L & 15;

    const int bidx = blockIdx.x;
    const int b    = bidx >> 4;           // batch
    const int hw0  = (bidx & 15) * 64;    // position tile base
    const float* zb = z + (size_t)b * C * HW + hw0;

    // ---- phase 1: cooperative transpose, wave w covers channels [w*64, w*64+64) ----
    // lane = token; 4 channels per iteration -> one packed ds_write_b64
    for (int c = w * 64; c < w * 64 + 64; c += 4) {
        float v0 = zb[(size_t)(c + 0) * HW + L];
        float v1 = zb[(size_t)(c + 1) * HW + L];
        float v2 = zb[(size_t)(c + 2) * HW + L];
        float v3 = zb[(size_t)(c + 3) * HW + L];
        ushort4 pk = { f2bf(v0), f2bf(v1), f2bf(v2), f2bf(v3) };
        *(ushort4*)&Zs[(c >> 3) * 512 + L * 8 + (c & 7)] = pk;
    }
    __syncthreads();

    // ---- phase 2: B-fragments into registers (held for whole K loop) + argmin init ----
    bf16x8 zfrag[4][8];   // [token tile][k-slice]: token = t*16+l15, ch = ks*32 + q*8 + j
#pragma unroll
    for (int t = 0; t < 4; ++t)
#pragma unroll
        for (int ks = 0; ks < 8; ++ks)
            zfrag[t][ks] = *(const bf16x8*)&Zs[(ks * 4 + q) * 512 + (t * 16 + l15) * 8];
    if (tid < 64) bestTok[tid] = 0xFFFFFFFFu;
    __syncthreads();   // bestTok init visible before any atomicMin

    // ---- phase 3: wave-private K loop, 4 chunks of 64 codes, no barriers ----
    unsigned int best[4] = {0xFFFFFFFFu, 0xFFFFFFFFu, 0xFFFFFFFFu, 0xFFFFFFFFu};

    for (int ch = 0; ch < 4; ++ch) {
        const int k0 = w * 256 + ch * 64;
        floatx4 acc[4][4];   // [m code tile][t token tile]
#pragma unroll
        for (int m = 0; m < 4; ++m)
#pragma unroll
            for (int t = 0; t < 4; ++t) acc[m][t] = (floatx4){0.f, 0.f, 0.f, 0.f};

#pragma unroll
        for (int ks = 0; ks < 8; ++ks) {
            U16 a[4];
#pragma unroll
            for (int m = 0; m < 4; ++m)
                a[m].u = *(const uint4*)(emb_bf + ((size_t)(k0 + m * 16 + l15) << 8) + ks * 32 + q * 8);
#pragma unroll
            for (int m = 0; m < 4; ++m)
#pragma unroll
                for (int t = 0; t < 4; ++t)
                    acc[m][t] = __builtin_amdgcn_mfma_f32_16x16x32_bf16(a[m].b, zfrag[t][ks], acc[m][t], 0, 0, 0);
        }

        // distances + packed argmin (d positive: float bits monotone; low 10 bits = code)
#pragma unroll
        for (int m = 0; m < 4; ++m) {
            const float4 eq = *(const float4*)&esq1[k0 + m * 16 + q * 4];
            const float eqa[4] = {eq.x, eq.y, eq.z, eq.w};
#pragma unroll
            for (int r = 0; r < 4; ++r) {
                const unsigned int code = (unsigned int)(k0 + m * 16 + q * 4 + r);
#pragma unroll
                for (int t = 0; t < 4; ++t) {
                    float d = fmaf(-2.0f, acc[m][t][r], eqa[r]);
                    unsigned int u = (__float_as_uint(d) & 0xFFFFFC00u) | code;
                    best[t] = best[t] < u ? best[t] : u;
                }
            }
        }
    }

    // ---- phase 4: butterfly across quads, then cross-wave LDS atomicMin ----
#pragma unroll
    for (int t = 0; t < 4; ++t) {
        unsigned int o = (unsigned int)__shfl_xor((int)best[t], 16, 64);
        best[t] = best[t] < o ? best[t] : o;
        o = (unsigned int)__shfl_xor((int)best[t], 32, 64);
        best[t] = best[t] < o ? best[t] : o;
    }
    if (q == 0) {
#pragma unroll
        for (int t = 0; t < 4; ++t)
            atomicMin(&bestTok[t * 16 + l15], best[t]);
    }
    __syncthreads();

    // ---- phase 5: gather code row (fp32), straight-through out, loss partials ----
    const int p  = tid & 63;   // token
    const int cq = tid >> 6;   // channel phase
    const int km = (int)(bestTok[p] & 1023u);
    const float* erow = emb + (size_t)km * C;
    float s_sq = 0.0f, s_d = 0.0f;
    const size_t base = (size_t)b * C * HW + hw0 + p;
    for (int c = cq; c < C; c += 4) {
        float ev = erow[c];
        float zv = z[base + (size_t)c * HW];
        float diff = ev - zv;                      // z_q - z
        out[base + (size_t)c * HW] = zv + diff;    // straight-through fwd value
        s_sq = fmaf(diff, diff, s_sq);
        s_d += diff;
    }
#pragma unroll
    for (int off = 32; off > 0; off >>= 1) {
        s_sq += __shfl_down(s_sq, off, 64);
        s_d  += __shfl_down(s_d,  off, 64);
    }
    if (L == 0) { wred[w] = s_sq; wred[4 + w] = s_d; }
    __syncthreads();

    // ---- phase 6: block partials -> global; last block finalizes the loss ----
    if (tid == 0) {
        float a = wred[0] + wred[1] + wred[2] + wred[3];
        float d = wred[4] + wred[5] + wred[6] + wred[7];
        atomicAdd(&acc_loss[0], a);
        atomicAdd(&acc_loss[1], d);
        __threadfence();
        unsigned int old = atomicAdd((unsigned int*)&acc_loss[2], 1u);
        if (old == 1023u) {
            float sa = atomicAdd(&acc_loss[0], 0.0f);   // coherent read
            float sd = atomicAdd(&acc_loss[1], 0.0f);
            out_loss[0] = sa * NTOT_INV + BETA * (sd * NTOT_INV);
        }
    }
}

extern "C" void kernel_launch(void* const* d_in, const int* in_sizes, int n_in,
                              void* d_out, int out_size, void* d_ws, size_t ws_size,
                              hipStream_t stream) {
    const float* z   = (const float*)d_in[0];   // [64,256,32,32]
    const float* emb = (const float*)d_in[1];   // [1024,256]
    float* out = (float*)d_out;                 // [16777216 z_q] + [1 loss]
    float* ws  = (float*)d_ws;
    float* acc  = ws;                               // [0]=sum_sq [1]=sum_d [2]=counter
    float* esq1 = ws + 64;                          // 1024 floats
    short* emb_bf = (short*)(ws + 64 + 1024);       // 1024*256 bf16 = 512 KB

    prep_kernel<<<dim3(K / 4), 256, 0, stream>>>(emb, emb_bf, esq1, acc);
    vq_main<<<dim3(1024), 256, 0, stream>>>(z, emb, emb_bf, esq1, out, acc,
                                            out + (size_t)B * C * HW);
}